// Round 3
// baseline (631.858 us; speedup 1.0000x reference)
//
#include <hip/hip_runtime.h>

// irreps linear: 256x0e + 128x1o + 64x2e, shared weights, bias on 0e.
// x: (200000, 960) f32; w: 86016 f32; b: 256 f32; out: (200000, 960) f32.
//
// Latency-bound fix: deep async pipeline via global_load_lds.
// 256 blocks (1/CU), 256 thr, 2x60KB LDS dbuf, grid-stride over 12500
// 16-row tiles. Each tile: stage next tile (15x16B async loads/thread,
// 60KB outstanding, zero VGPR) while computing current from LDS.
// Wave roles: wv0/1 = b0 halves, wv2 = b1, wv3 = b2. LDS chunk XOR-swizzle
// (3-bit row XOR) applied on BOTH global source and LDS read (linear dest).
// Stores: round-2-validated vectorized maps, nontemporal.

typedef short frag8 __attribute__((ext_vector_type(8)));   // 8 bf16
typedef float f32x4 __attribute__((ext_vector_type(4)));

#define NTILES 12500
#define NBLOCKS 256
#define TILE_BYTES 61440      // 16 rows * 3840 B
#define ROW_BYTES 3840

static __device__ __forceinline__ short f2bf(float f) {
    union { float f; unsigned u; } v; v.f = f;
    unsigned r = (v.u + 0x7FFFu + ((v.u >> 16) & 1u)) >> 16;  // RNE
    return (short)r;
}

#define MFMA(a, b, c) __builtin_amdgcn_mfma_f32_16x16x32_bf16((a), (b), (c), 0, 0, 0)

// ---- weight prep: unchanged (validated rounds 1-2). frag f, lane l, reg j:
// k = 32*s + 4*(l>>4) + (j&3) + 16*(j>>2), w = nt*16 + (l&15).
__global__ __launch_bounds__(256) void prep_kernel(const float* __restrict__ w,
                                                   short* __restrict__ wf) {
    int e = blockIdx.x * 256 + threadIdx.x;   // 0..86015
    int f = e >> 9;
    int r = e & 511;
    int l = r >> 3, j = r & 7;
    int l15 = l & 15, lg = l >> 4;
    int kk = 4 * lg + (j & 3) + 16 * (j >> 2);
    int u, wc, woff, mul; float scale;
    if (f < 128) {
        int nt = f >> 3, s = f & 7;
        u = 32 * s + kk; wc = nt * 16 + l15; woff = 0;     mul = 256; scale = 0.0625f;
    } else if (f < 160) {
        int g = f - 128, nt = g >> 2, s = g & 3;
        u = 32 * s + kk; wc = nt * 16 + l15; woff = 65536; mul = 128; scale = 0.088388347648318447f;
    } else {
        int g = f - 160, nt = g >> 1, s = g & 1;
        u = 32 * s + kk; wc = nt * 16 + l15; woff = 81920; mul = 64;  scale = 0.125f;
    }
    wf[e] = f2bf(scale * w[woff + u * mul + wc]);
}

static __device__ __forceinline__ void gload_lds16(const void* g, void* l) {
    __builtin_amdgcn_global_load_lds(
        (const __attribute__((address_space(1))) unsigned int*)g,
        (__attribute__((address_space(3))) unsigned int*)l, 16, 0, 0);
}

__global__ __launch_bounds__(256, 1) void lin_fused(const float* __restrict__ x,
                                                    const short* __restrict__ wf,
                                                    const float* __restrict__ bias,
                                                    float* __restrict__ out) {
    extern __shared__ __align__(16) char smem[];
    const int tid  = threadIdx.x;
    const int lane = tid & 63;
    const int wv   = tid >> 6;
    const int l15  = lane & 15;
    const int lg   = lane >> 4;
    const int swz  = l15 & 7;
    const frag8* __restrict__ wfr = (const frag8*)wf;

    // prologue: stage tile blockIdx.x into buf0
    {
        const char* xb = (const char*)x + (long)blockIdx.x * TILE_BYTES;
        #pragma unroll
        for (int j = 0; j < 15; ++j) {
            int c  = j * 256 + tid;           // dest chunk (linear in tile)
            int r  = c / 240;                 // dest row
            int cc = c - r * 240;             // dest in-row chunk
            int g  = cc ^ (r & 7);            // inverse-swizzled source chunk
            gload_lds16(xb + (long)r * ROW_BYTES + (g << 4),
                        smem + (j * 256 + wv * 64) * 16);
        }
    }
    __syncthreads();

    int cur = 0;
    for (int t = blockIdx.x; t < NTILES; t += NBLOCKS) {
        // ---- stage tile t+NBLOCKS into buf cur^1 (async, no regs) ----
        if (t + NBLOCKS < NTILES) {
            const char* xb = (const char*)x + (long)(t + NBLOCKS) * TILE_BYTES;
            char* sb1 = smem + (cur ^ 1) * TILE_BYTES;
            #pragma unroll
            for (int j = 0; j < 15; ++j) {
                int c  = j * 256 + tid;
                int r  = c / 240;
                int cc = c - r * 240;
                int g  = cc ^ (r & 7);
                gload_lds16(xb + (long)r * ROW_BYTES + (g << 4),
                            sb1 + (j * 256 + wv * 64) * 16);
            }
        }

        // ---- compute tile t from buf cur ----
        const char* sb = smem + cur * TILE_BYTES + l15 * ROW_BYTES;  // this lane's row
        float* __restrict__ outr = out + (long)(t * 16 + l15) * 960;
        // swizzled chunk read helper (expanded inline below): chunk cc ->
        //   *(f32x4*)(sb + ((cc ^ swz) << 4))
        #define LDC(cc) (*(const f32x4*)(sb + (((cc) ^ swz) << 4)))

        if (wv < 2) {
            // ===== block0 half: out cols [wv*128, wv*128+128), K=256 =====
            frag8 a0[8];
            #pragma unroll
            for (int s = 0; s < 8; ++s) {
                const f32x4 v0 = LDC(8 * s + lg);
                const f32x4 v1 = LDC(8 * s + 4 + lg);
                frag8 a;
                a[0] = f2bf(v0[0]); a[1] = f2bf(v0[1]); a[2] = f2bf(v0[2]); a[3] = f2bf(v0[3]);
                a[4] = f2bf(v1[0]); a[5] = f2bf(v1[1]); a[6] = f2bf(v1[2]); a[7] = f2bf(v1[3]);
                a0[s] = a;
            }
            const int nt0 = wv * 8;
            #pragma unroll
            for (int q = 0; q < 8; ++q) {
                const int nt = nt0 + q;
                f32x4 acc = {0.f, 0.f, 0.f, 0.f};
                #pragma unroll
                for (int s = 0; s < 8; ++s) {
                    frag8 bw = wfr[(nt * 8 + s) * 64 + lane];
                    acc = MFMA(bw, a0[s], acc);           // D[w][atom]
                }
                const f32x4 bv = *(const f32x4*)(bias + nt * 16 + 4 * lg);
                f32x4 st = {acc[0] + bv[0], acc[1] + bv[1], acc[2] + bv[2], acc[3] + bv[3]};
                __builtin_nontemporal_store(st, (f32x4*)(outr + nt * 16 + 4 * lg));
            }
        } else if (wv == 2) {
            // ===== block1: out cols 256..639 (col = 256 + 3u + i) =====
            frag8 a1[12];
            #pragma unroll
            for (int s = 0; s < 4; ++s) {
                #pragma unroll
                for (int h = 0; h < 2; ++h) {
                    const int cb = 64 + 24 * s + 12 * h + 3 * lg;
                    const f32x4 q0 = LDC(cb);
                    const f32x4 q1 = LDC(cb + 1);
                    const f32x4 q2 = LDC(cb + 2);
                    const int j0 = 4 * h;
                    a1[0 + s][j0 + 0] = f2bf(q0[0]); a1[0 + s][j0 + 1] = f2bf(q0[3]);
                    a1[0 + s][j0 + 2] = f2bf(q1[2]); a1[0 + s][j0 + 3] = f2bf(q2[1]);
                    a1[4 + s][j0 + 0] = f2bf(q0[1]); a1[4 + s][j0 + 1] = f2bf(q1[0]);
                    a1[4 + s][j0 + 2] = f2bf(q1[3]); a1[4 + s][j0 + 3] = f2bf(q2[2]);
                    a1[8 + s][j0 + 0] = f2bf(q0[2]); a1[8 + s][j0 + 1] = f2bf(q1[1]);
                    a1[8 + s][j0 + 2] = f2bf(q2[0]); a1[8 + s][j0 + 3] = f2bf(q2[3]);
                }
            }
            #pragma unroll 2
            for (int nt = 0; nt < 8; ++nt) {
                f32x4 c0 = {0.f,0.f,0.f,0.f}, c1 = {0.f,0.f,0.f,0.f}, c2 = {0.f,0.f,0.f,0.f};
                #pragma unroll
                for (int s = 0; s < 4; ++s) {
                    frag8 bw = wfr[(128 + nt * 4 + s) * 64 + lane];
                    c0 = MFMA(bw, a1[0 + s], c0);
                    c1 = MFMA(bw, a1[4 + s], c1);
                    c2 = MFMA(bw, a1[8 + s], c2);
                }
                float* o = outr + 256 + 3 * (nt * 16 + 4 * lg);
                f32x4 v0 = {c0[0], c1[0], c2[0], c0[1]};
                f32x4 v1 = {c1[1], c2[1], c0[2], c1[2]};
                f32x4 v2 = {c2[2], c0[3], c1[3], c2[3]};
                __builtin_nontemporal_store(v0, (f32x4*)(o));
                __builtin_nontemporal_store(v1, (f32x4*)(o + 4));
                __builtin_nontemporal_store(v2, (f32x4*)(o + 8));
            }
        } else {
            // ===== block2: out cols 640..959 (col = 640 + 5u + i) =====
            frag8 a2[10];
            #pragma unroll
            for (int s = 0; s < 2; ++s) {
                #pragma unroll
                for (int h = 0; h < 2; ++h) {
                    const int cb = 160 + 40 * s + 20 * h + 5 * lg;
                    const f32x4 q0 = LDC(cb);
                    const f32x4 q1 = LDC(cb + 1);
                    const f32x4 q2 = LDC(cb + 2);
                    const f32x4 q3 = LDC(cb + 3);
                    const f32x4 q4 = LDC(cb + 4);
                    const int j0 = 4 * h;
                    a2[0 + s][j0 + 0] = f2bf(q0[0]); a2[0 + s][j0 + 1] = f2bf(q1[1]);
                    a2[0 + s][j0 + 2] = f2bf(q2[2]); a2[0 + s][j0 + 3] = f2bf(q3[3]);
                    a2[2 + s][j0 + 0] = f2bf(q0[1]); a2[2 + s][j0 + 1] = f2bf(q1[2]);
                    a2[2 + s][j0 + 2] = f2bf(q2[3]); a2[2 + s][j0 + 3] = f2bf(q4[0]);
                    a2[4 + s][j0 + 0] = f2bf(q0[2]); a2[4 + s][j0 + 1] = f2bf(q1[3]);
                    a2[4 + s][j0 + 2] = f2bf(q3[0]); a2[4 + s][j0 + 3] = f2bf(q4[1]);
                    a2[6 + s][j0 + 0] = f2bf(q0[3]); a2[6 + s][j0 + 1] = f2bf(q2[0]);
                    a2[6 + s][j0 + 2] = f2bf(q3[1]); a2[6 + s][j0 + 3] = f2bf(q4[2]);
                    a2[8 + s][j0 + 0] = f2bf(q1[0]); a2[8 + s][j0 + 1] = f2bf(q2[1]);
                    a2[8 + s][j0 + 2] = f2bf(q3[2]); a2[8 + s][j0 + 3] = f2bf(q4[3]);
                }
            }
            #pragma unroll 2
            for (int nt = 0; nt < 4; ++nt) {
                f32x4 c0 = {0.f,0.f,0.f,0.f}, c1 = {0.f,0.f,0.f,0.f}, c2 = {0.f,0.f,0.f,0.f},
                      c3 = {0.f,0.f,0.f,0.f}, c4 = {0.f,0.f,0.f,0.f};
                #pragma unroll
                for (int s = 0; s < 2; ++s) {
                    frag8 bw = wfr[(160 + nt * 2 + s) * 64 + lane];
                    c0 = MFMA(bw, a2[0 + s], c0);
                    c1 = MFMA(bw, a2[2 + s], c1);
                    c2 = MFMA(bw, a2[4 + s], c2);
                    c3 = MFMA(bw, a2[6 + s], c3);
                    c4 = MFMA(bw, a2[8 + s], c4);
                }
                float* o = outr + 640 + 5 * (nt * 16 + 4 * lg);
                f32x4 v0 = {c0[0], c1[0], c2[0], c3[0]};
                f32x4 v1 = {c4[0], c0[1], c1[1], c2[1]};
                f32x4 v2 = {c3[1], c4[1], c0[2], c1[2]};
                f32x4 v3 = {c2[2], c3[2], c4[2], c0[3]};
                f32x4 v4 = {c1[3], c2[3], c3[3], c4[3]};
                __builtin_nontemporal_store(v0, (f32x4*)(o));
                __builtin_nontemporal_store(v1, (f32x4*)(o + 4));
                __builtin_nontemporal_store(v2, (f32x4*)(o + 8));
                __builtin_nontemporal_store(v3, (f32x4*)(o + 12));
                __builtin_nontemporal_store(v4, (f32x4*)(o + 16));
            }
        }
        #undef LDC

        __syncthreads();   // drains vmcnt (stage t+NBLOCKS complete) + LDS reads done
        cur ^= 1;
    }
}

extern "C" void kernel_launch(void* const* d_in, const int* in_sizes, int n_in,
                              void* d_out, int out_size, void* d_ws, size_t ws_size,
                              hipStream_t stream) {
    const float* x = (const float*)d_in[0];
    const float* w = (const float*)d_in[1];
    const float* b = (const float*)d_in[2];
    float* out = (float*)d_out;
    short* wf  = (short*)d_ws;          // 86016 bf16 = 172032 B of scratch

    hipLaunchKernelGGL(prep_kernel, dim3(336), dim3(256), 0, stream, w, wf);

    (void)hipFuncSetAttribute((const void*)lin_fused,
                              hipFuncAttributeMaxDynamicSharedMemorySize,
                              2 * TILE_BYTES);
    hipLaunchKernelGGL(lin_fused, dim3(NBLOCKS), dim3(256), 2 * TILE_BYTES, stream,
                       x, wf, b, out);
}

// Round 4
// 381.065 us; speedup vs baseline: 1.6581x; 1.6581x over previous
//
#include <hip/hip_runtime.h>

// irreps linear: 256x0e + 128x1o + 64x2e, shared weights, bias on 0e.
// x: (200000, 960) f32; w: 86016 f32; b: 256 f32; out: (200000, 960) f32.
//
// Round 4: per-(tile, family) blocks. grid (12500, 3); family f handles irrep
// block f's column slice of a 16-row tile. Stage slice via global_load_lds
// (16/24/20 KB, exact cache-line partition of each row), one __syncthreads
// (vmcnt drain), MFMA compute, plain cached float4 stores (L2 merges).
// Static 24KB LDS -> 5-6 blocks/CU so stage drains overlap sibling compute.
// Numerics (XOR chunk swizzle, fragment maps, store maps) identical to the
// validated round-2/3 kernels.

typedef short frag8 __attribute__((ext_vector_type(8)));   // 8 bf16
typedef float f32x4 __attribute__((ext_vector_type(4)));

static __device__ __forceinline__ short f2bf(float f) {
    union { float f; unsigned u; } v; v.f = f;
    unsigned r = (v.u + 0x7FFFu + ((v.u >> 16) & 1u)) >> 16;  // RNE
    return (short)r;
}

#define MFMA(a, b, c) __builtin_amdgcn_mfma_f32_16x16x32_bf16((a), (b), (c), 0, 0, 0)

// ---- weight prep: unchanged (validated rounds 1-3). frag f, lane l, reg j:
// k = 32*s + 4*(l>>4) + (j&3) + 16*(j>>2), w = nt*16 + (l&15).
__global__ __launch_bounds__(256) void prep_kernel(const float* __restrict__ w,
                                                   short* __restrict__ wf) {
    int e = blockIdx.x * 256 + threadIdx.x;   // 0..86015
    int f = e >> 9;
    int r = e & 511;
    int l = r >> 3, j = r & 7;
    int l15 = l & 15, lg = l >> 4;
    int kk = 4 * lg + (j & 3) + 16 * (j >> 2);
    int u, wc, woff, mul; float scale;
    if (f < 128) {
        int nt = f >> 3, s = f & 7;
        u = 32 * s + kk; wc = nt * 16 + l15; woff = 0;     mul = 256; scale = 0.0625f;
    } else if (f < 160) {
        int g = f - 128, nt = g >> 2, s = g & 3;
        u = 32 * s + kk; wc = nt * 16 + l15; woff = 65536; mul = 128; scale = 0.088388347648318447f;
    } else {
        int g = f - 160, nt = g >> 1, s = g & 1;
        u = 32 * s + kk; wc = nt * 16 + l15; woff = 81920; mul = 64;  scale = 0.125f;
    }
    wf[e] = f2bf(scale * w[woff + u * mul + wc]);
}

static __device__ __forceinline__ void gload_lds16(const void* g, void* l) {
    __builtin_amdgcn_global_load_lds(
        (const __attribute__((address_space(1))) unsigned int*)g,
        (__attribute__((address_space(3))) unsigned int*)l, 16, 0, 0);
}

__global__ __launch_bounds__(256) void lin_tile(const float* __restrict__ x,
                                                const short* __restrict__ wf,
                                                const float* __restrict__ bias,
                                                float* __restrict__ out) {
    __shared__ __align__(16) char smem[24576];
    const int tid  = threadIdx.x;
    const int lane = tid & 63;
    const int wv   = tid >> 6;
    const int l15  = lane & 15;
    const int lg   = lane >> 4;
    const int fam  = blockIdx.y;
    const long rowbase = (long)blockIdx.x * 16;
    const char* __restrict__ xb = (const char*)x + rowbase * 3840;
    float* __restrict__ outr = out + (rowbase + l15) * 960;
    const frag8* __restrict__ wfr = (const frag8*)wf;
    const int swz = l15 & 7;

    // ---- stage this family's column slice (linear LDS dest, inverse-swizzled
    //      global source chunk: LDS[r][cc] = X[r][cc ^ (r&7)]) ----
    if (fam == 0) {              // cols 0..1023 B, C=64 chunks, 16 KB
        #pragma unroll
        for (int j = 0; j < 4; ++j) {
            int c  = j * 256 + tid;
            int r  = c >> 6;
            int cc = c & 63;
            int g  = cc ^ (r & 7);
            gload_lds16(xb + r * 3840 + (g << 4),
                        smem + (j * 256 + wv * 64) * 16);
        }
    } else if (fam == 1) {       // cols 1024..2559 B, C=96 chunks, 24 KB
        #pragma unroll
        for (int j = 0; j < 6; ++j) {
            int c  = j * 256 + tid;
            int r  = c / 96;
            int cc = c - r * 96;
            int g  = cc ^ (r & 7);
            gload_lds16(xb + r * 3840 + 1024 + (g << 4),
                        smem + (j * 256 + wv * 64) * 16);
        }
    } else {                     // cols 2560..3839 B, C=80 chunks, 20 KB
        #pragma unroll
        for (int j = 0; j < 5; ++j) {
            int c  = j * 256 + tid;
            int r  = c / 80;
            int cc = c - r * 80;
            int g  = cc ^ (r & 7);
            gload_lds16(xb + r * 3840 + 2560 + (g << 4),
                        smem + (j * 256 + wv * 64) * 16);
        }
    }
    __syncthreads();   // drains vmcnt(0): slice resident in LDS

    if (fam == 0) {
        // ===== block0: out cols 0..255, K=256; wave wv -> nt = 4wv..4wv+3 ====
        const char* sb = smem + l15 * 1024;
        #define LDC0(cc) (*(const f32x4*)(sb + (((cc) ^ swz) << 4)))
        frag8 a0[8];
        #pragma unroll
        for (int s = 0; s < 8; ++s) {
            const f32x4 v0 = LDC0(8 * s + lg);
            const f32x4 v1 = LDC0(8 * s + 4 + lg);
            frag8 a;
            a[0] = f2bf(v0[0]); a[1] = f2bf(v0[1]); a[2] = f2bf(v0[2]); a[3] = f2bf(v0[3]);
            a[4] = f2bf(v1[0]); a[5] = f2bf(v1[1]); a[6] = f2bf(v1[2]); a[7] = f2bf(v1[3]);
            a0[s] = a;
        }
        #pragma unroll
        for (int q = 0; q < 4; ++q) {
            const int nt = 4 * wv + q;
            f32x4 acc = {0.f, 0.f, 0.f, 0.f};
            #pragma unroll
            for (int s = 0; s < 8; ++s) {
                frag8 bw = wfr[(nt * 8 + s) * 64 + lane];
                acc = MFMA(bw, a0[s], acc);            // D[w][atom]
            }
            const f32x4 bv = *(const f32x4*)(bias + nt * 16 + 4 * lg);
            f32x4 st = {acc[0] + bv[0], acc[1] + bv[1], acc[2] + bv[2], acc[3] + bv[3]};
            *(f32x4*)(outr + nt * 16 + 4 * lg) = st;
        }
        #undef LDC0
    } else if (fam == 1) {
        // ===== block1: out cols 256..639 (col = 256+3u+i); nt = 2wv..2wv+1 ===
        const char* sb = smem + l15 * 1536;
        #define LDC1(cc) (*(const f32x4*)(sb + (((cc) ^ swz) << 4)))
        frag8 a1[12];
        #pragma unroll
        for (int s = 0; s < 4; ++s) {
            #pragma unroll
            for (int h = 0; h < 2; ++h) {
                const int cb = 24 * s + 12 * h + 3 * lg;
                const f32x4 q0 = LDC1(cb);
                const f32x4 q1 = LDC1(cb + 1);
                const f32x4 q2 = LDC1(cb + 2);
                const int j0 = 4 * h;
                a1[0 + s][j0 + 0] = f2bf(q0[0]); a1[0 + s][j0 + 1] = f2bf(q0[3]);
                a1[0 + s][j0 + 2] = f2bf(q1[2]); a1[0 + s][j0 + 3] = f2bf(q2[1]);
                a1[4 + s][j0 + 0] = f2bf(q0[1]); a1[4 + s][j0 + 1] = f2bf(q1[0]);
                a1[4 + s][j0 + 2] = f2bf(q1[3]); a1[4 + s][j0 + 3] = f2bf(q2[2]);
                a1[8 + s][j0 + 0] = f2bf(q0[2]); a1[8 + s][j0 + 1] = f2bf(q1[1]);
                a1[8 + s][j0 + 2] = f2bf(q2[0]); a1[8 + s][j0 + 3] = f2bf(q2[3]);
            }
        }
        #undef LDC1
        #pragma unroll
        for (int q = 0; q < 2; ++q) {
            const int nt = 2 * wv + q;
            f32x4 c0 = {0.f,0.f,0.f,0.f}, c1 = {0.f,0.f,0.f,0.f}, c2 = {0.f,0.f,0.f,0.f};
            #pragma unroll
            for (int s = 0; s < 4; ++s) {
                frag8 bw = wfr[(128 + nt * 4 + s) * 64 + lane];
                c0 = MFMA(bw, a1[0 + s], c0);
                c1 = MFMA(bw, a1[4 + s], c1);
                c2 = MFMA(bw, a1[8 + s], c2);
            }
            float* o = outr + 256 + 3 * (nt * 16 + 4 * lg);
            f32x4 v0 = {c0[0], c1[0], c2[0], c0[1]};
            f32x4 v1 = {c1[1], c2[1], c0[2], c1[2]};
            f32x4 v2 = {c2[2], c0[3], c1[3], c2[3]};
            *(f32x4*)(o)     = v0;
            *(f32x4*)(o + 4) = v1;
            *(f32x4*)(o + 8) = v2;
        }
    } else {
        // ===== block2: out cols 640..959 (col = 640+5u+i); nt = wv ===========
        const char* sb = smem + l15 * 1280;
        #define LDC2(cc) (*(const f32x4*)(sb + (((cc) ^ swz) << 4)))
        frag8 a2[10];
        #pragma unroll
        for (int s = 0; s < 2; ++s) {
            #pragma unroll
            for (int h = 0; h < 2; ++h) {
                const int cb = 40 * s + 20 * h + 5 * lg;
                const f32x4 q0 = LDC2(cb);
                const f32x4 q1 = LDC2(cb + 1);
                const f32x4 q2 = LDC2(cb + 2);
                const f32x4 q3 = LDC2(cb + 3);
                const f32x4 q4 = LDC2(cb + 4);
                const int j0 = 4 * h;
                a2[0 + s][j0 + 0] = f2bf(q0[0]); a2[0 + s][j0 + 1] = f2bf(q1[1]);
                a2[0 + s][j0 + 2] = f2bf(q2[2]); a2[0 + s][j0 + 3] = f2bf(q3[3]);
                a2[2 + s][j0 + 0] = f2bf(q0[1]); a2[2 + s][j0 + 1] = f2bf(q1[2]);
                a2[2 + s][j0 + 2] = f2bf(q2[3]); a2[2 + s][j0 + 3] = f2bf(q4[0]);
                a2[4 + s][j0 + 0] = f2bf(q0[2]); a2[4 + s][j0 + 1] = f2bf(q1[3]);
                a2[4 + s][j0 + 2] = f2bf(q3[0]); a2[4 + s][j0 + 3] = f2bf(q4[1]);
                a2[6 + s][j0 + 0] = f2bf(q0[3]); a2[6 + s][j0 + 1] = f2bf(q2[0]);
                a2[6 + s][j0 + 2] = f2bf(q3[1]); a2[6 + s][j0 + 3] = f2bf(q4[2]);
                a2[8 + s][j0 + 0] = f2bf(q1[0]); a2[8 + s][j0 + 1] = f2bf(q2[1]);
                a2[8 + s][j0 + 2] = f2bf(q3[2]); a2[8 + s][j0 + 3] = f2bf(q4[3]);
            }
        }
        #undef LDC2
        {
            const int nt = wv;
            f32x4 c0 = {0.f,0.f,0.f,0.f}, c1 = {0.f,0.f,0.f,0.f}, c2 = {0.f,0.f,0.f,0.f},
                  c3 = {0.f,0.f,0.f,0.f}, c4 = {0.f,0.f,0.f,0.f};
            #pragma unroll
            for (int s = 0; s < 2; ++s) {
                frag8 bw = wfr[(160 + nt * 2 + s) * 64 + lane];
                c0 = MFMA(bw, a2[0 + s], c0);
                c1 = MFMA(bw, a2[2 + s], c1);
                c2 = MFMA(bw, a2[4 + s], c2);
                c3 = MFMA(bw, a2[6 + s], c3);
                c4 = MFMA(bw, a2[8 + s], c4);
            }
            float* o = outr + 640 + 5 * (nt * 16 + 4 * lg);
            f32x4 v0 = {c0[0], c1[0], c2[0], c3[0]};
            f32x4 v1 = {c4[0], c0[1], c1[1], c2[1]};
            f32x4 v2 = {c3[1], c4[1], c0[2], c1[2]};
            f32x4 v3 = {c2[2], c3[2], c4[2], c0[3]};
            f32x4 v4 = {c1[3], c2[3], c3[3], c4[3]};
            *(f32x4*)(o)      = v0;
            *(f32x4*)(o + 4)  = v1;
            *(f32x4*)(o + 8)  = v2;
            *(f32x4*)(o + 12) = v3;
            *(f32x4*)(o + 16) = v4;
        }
    }
}

extern "C" void kernel_launch(void* const* d_in, const int* in_sizes, int n_in,
                              void* d_out, int out_size, void* d_ws, size_t ws_size,
                              hipStream_t stream) {
    const float* x = (const float*)d_in[0];
    const float* w = (const float*)d_in[1];
    const float* b = (const float*)d_in[2];
    float* out = (float*)d_out;
    short* wf  = (short*)d_ws;          // 86016 bf16 = 172032 B of scratch

    hipLaunchKernelGGL(prep_kernel, dim3(336), dim3(256), 0, stream, w, wf);
    // 12500 16-row tiles x 3 irrep families
    hipLaunchKernelGGL(lin_tile, dim3(12500, 3), dim3(256), 0, stream,
                       x, wf, b, out);
}